// Round 6
// baseline (5049.712 us; speedup 1.0000x reference)
//
#include <hip/hip_runtime.h>
#include <hip/hip_bf16.h>
#include <hip/hip_fp16.h>

// ============================================================================
// 2-layer LSTM (TF BasicLSTMCell, forget_bias=1), B=32, T=2048, D=H=256.
// R11: two-batch interleave — hide handoff latency under the OTHER batch's
//   compute. Post-mortems: R6 (reg pinning: null), R7 (half the on-chain dot:
//   null), R8/R9 (asm sc0 poll: container death), R10 (WG-scope CAS probe:
//   failed CAS still dirties the L2 line -> 1.8GB writebacks, +28% time).
//   Conclusion: the ~2500cy publish->discover latency of the agent-scope
//   handoff is NOT reducible from HIP source. So hide it instead:
//     * 128 WGs = 2L x 4slice x 16 batch-pairs, 512 thr. Pair (b, b+16)
//       shares (L,s) -> SAME 128 weight VGPRs, zero extra weight cost.
//     * per iteration: full R7 step for b1, then full R7 step for b2.
//       Each batch's publish->next-poll gap now contains the other batch's
//       entire step (~1200cy dots/bars/elem) -> most of the latency is
//       under useful work. Occupancy drops to 128 CUs busy - irrelevant,
//       the problem is latency-bound, not throughput-bound.
//     * protocol reverted to PROVEN R7 agent-scope-only tagged words
//       (t<<16|f16, poison-safe); no asm, no CAS, no dual-publish.
//   Unchanged: A/B split dot, x(t+1) prefetch, wave0 own-slice LDS
//   self-stage (pollers handle 192 remote cols), H1 write-once trace,
//   H2 depth-4 ring (skew<=1 unchanged), prep/Wrec layout, detect.
// ============================================================================

typedef _Float16 half_t;
typedef __attribute__((ext_vector_type(2))) _Float16 h2v;

static __device__ __forceinline__ float bf2f(unsigned short u) {
  union { unsigned u; float f; } v; v.u = ((unsigned)u) << 16; return v.f;
}
static __device__ __forceinline__ unsigned short f2bf(float f) {
  union { float f; unsigned u; } v; v.f = f;
  unsigned r = v.u + 0x7fffu + ((v.u >> 16) & 1u);
  return (unsigned short)(r >> 16);
}
static __device__ __forceinline__ float ldw(const void* p, long i, int fp32) {
  return fp32 ? ((const float*)p)[i] : bf2f(((const unsigned short*)p)[i]);
}
static __device__ __forceinline__ unsigned short f16b(float f) {
  return __builtin_bit_cast(unsigned short, (half_t)f);
}
static __device__ __forceinline__ h2v BC(unsigned u) {
  return __builtin_bit_cast(h2v, u);
}
static __device__ __forceinline__ float rcpf(float x) { return __builtin_amdgcn_rcpf(x); }
static __device__ __forceinline__ float sigm(float x) { return rcpf(1.f + __expf(-x)); }
static __device__ __forceinline__ float tanh_(float x) {
  float e = __expf(-2.f * fabsf(x));
  float t = (1.f - e) * rcpf(1.f + e);
  return copysignf(t, x);
}
static __device__ __forceinline__ float fdot2(h2v a, h2v b, float c) {
#if __has_builtin(__builtin_amdgcn_fdot2)
  return __builtin_amdgcn_fdot2(a, b, c, false);
#else
  return c + (float)a.x * (float)b.x + (float)a.y * (float)b.y;
#endif
}
static __device__ __forceinline__ unsigned ald(const unsigned* p) {
  return __hip_atomic_load(p, __ATOMIC_RELAXED, __HIP_MEMORY_SCOPE_AGENT);
}
// R7's proven poll: 4 outstanding agent-scope loads per round.
static __device__ __forceinline__ unsigned poll_tag(const unsigned* p, unsigned tg) {
  unsigned v = ald(p);
  while ((v >> 16) != tg) {
    unsigned a = ald(p);
    unsigned b = ald(p);
    unsigned c = ald(p);
    unsigned d = ald(p);
    if ((a >> 16) == tg) { v = a; break; }
    if ((b >> 16) == tg) { v = b; break; }
    if ((c >> 16) == tg) { v = c; break; }
    v = d;
  }
  return v;
}

// ---------------------------------------------------------------- detect ----
__global__ __launch_bounds__(256) void detect(const unsigned short* __restrict__ x,
                                              int* __restrict__ flag) {
  __shared__ int cnt;
  if (threadIdx.x == 0) cnt = 0;
  __syncthreads();
  int c = 0;
#pragma unroll
  for (int i = 0; i < 8; ++i) {
    unsigned short u = x[threadIdx.x * 8 + i];
    c += (((u >> 7) & 0xFF) >= 192) ? 1 : 0;
  }
  atomicAdd(&cnt, c);
  __syncthreads();
  if (threadIdx.x == 0) *flag = (cnt > 16) ? 1 : 0;
}

// ------------------------------------------------------------------ prep ----
// task0 (y=0): Wrec packed u32 words. u = (sL*512 + tid)*128 + i, sL=L*4+s.
//   kq=tid>>8, c=tid&255, col=(c>>6)*256 + s*64 + (c&63).
//   word i -> part p=i>>6 (0=feed-forward rows 0..255, 1=recurrent rows
//   256..511), ii=i&63, rows p*256 + kq*128 + 2*ii, +1. word = lo | hi<<16.
// task1 (y=1): biases -> fp32.
// ----------------------------------------------------------------------------
__global__ __launch_bounds__(256) void prep(
    const void* __restrict__ W0, const void* __restrict__ W1,
    const void* __restrict__ b0, const void* __restrict__ b1,
    const int* __restrict__ dtf,
    unsigned* __restrict__ Wrec, float* __restrict__ bias0,
    float* __restrict__ bias1)
{
  const int fp32 = *dtf;
  int id = blockIdx.x * 256 + threadIdx.x;
  if (blockIdx.y == 0) {
    int i  = id & 127;
    int tid = (id >> 7) & 511;
    int sL = id >> 16;                 // 0..7 = L*4+s
    int L = sL >> 2, s = sL & 3;
    int kq = tid >> 8, c = tid & 255;
    int col = ((c >> 6) << 8) + s * 64 + (c & 63);
    int p  = i >> 6, ii = i & 63;
    long r0 = (long)(p * 256 + kq * 128 + 2 * ii) * 1024 + col;
    const void* W = L ? W1 : W0;
    unsigned lo = f16b(ldw(W, r0, fp32));
    unsigned hi = f16b(ldw(W, r0 + 1024, fp32));
    Wrec[id] = lo | (hi << 16);
  } else {
    if (id < 1024)       bias0[id] = ldw(b0, id, fp32);
    else if (id < 2048)  bias1[id - 1024] = ldw(b1, id - 1024, fp32);
  }
}

// ----------------------------------------------------------------- recur ----
__global__ __launch_bounds__(512) void recur(
    const void* __restrict__ x, const unsigned* __restrict__ Wrec,
    const float* __restrict__ bias0, const float* __restrict__ bias1,
    unsigned* H1T, unsigned* H2R,
    void* __restrict__ dout, const int* __restrict__ dtf)
{
  const int fp32 = *dtf;
  const int bi = blockIdx.x;                 // 0..127
  const int L = bi >> 6, s = (bi >> 4) & 3, pb = bi & 15;
  const int b1 = pb, b2 = pb + 16;
  const int sL = L * 4 + s;
  const int tid = threadIdx.x;
  const int kq = tid >> 8, c = tid & 255;
  const int abase = kq << 4;        // A-dot hbuf base (rows 0..255)
  const int bbase = 32 + (kq << 4); // B-dot hbuf base (rows 256..511)

  __shared__ __align__(16) unsigned short hbufh[2][512];
  __shared__ float part[2][2][256];
  __shared__ float bg[256];

  // ---- weights: shared by BOTH batches of the pair (same L,s) ----
  const uint4* wp4 = (const uint4*)Wrec + ((size_t)sL * 512 + tid) * 32;
  uint4 w00 = wp4[0],  w01 = wp4[1],  w02 = wp4[2],  w03 = wp4[3];
  uint4 w04 = wp4[4],  w05 = wp4[5],  w06 = wp4[6],  w07 = wp4[7];
  uint4 w08 = wp4[8],  w09 = wp4[9],  w10 = wp4[10], w11 = wp4[11];
  uint4 w12 = wp4[12], w13 = wp4[13], w14 = wp4[14], w15 = wp4[15];
  uint4 w16 = wp4[16], w17 = wp4[17], w18 = wp4[18], w19 = wp4[19];
  uint4 w20 = wp4[20], w21 = wp4[21], w22 = wp4[22], w23 = wp4[23];
  uint4 w24 = wp4[24], w25 = wp4[25], w26 = wp4[26], w27 = wp4[27];
  uint4 w28 = wp4[28], w29 = wp4[29], w30 = wp4[30], w31 = wp4[31];

  if (tid < 256) {
    int scol = ((c >> 6) << 8) + s * 64 + (c & 63);
    bg[c] = (L ? bias1 : bias0)[scol];
  }

  float cst1 = 0.f, cst2 = 0.f;
  float xv1 = 0.f, xv2 = 0.f;

  // ---- prologue: stage A(0) both batches, zero B, prefetch x(1) ----
  if (tid < 256) {
    if (!L) {
      size_t xi1 = (size_t)b1 * 2048 * 256 + tid;
      hbufh[0][tid] = f16b(ldw(x, xi1, fp32));
      xv1 = ldw(x, xi1 + 256, fp32);
      size_t xi2 = (size_t)b2 * 2048 * 256 + tid;
      hbufh[1][tid] = f16b(ldw(x, xi2, fp32));
      xv2 = ldw(x, xi2 + 256, fp32);
    } else {
      hbufh[0][tid] = (unsigned short)poll_tag(H1T + (size_t)b1 * 256 + tid, 0u);
      hbufh[1][tid] = (unsigned short)poll_tag(H1T + (size_t)b2 * 256 + tid, 0u);
    }
  } else {
    hbufh[0][tid] = 0;
    hbufh[1][tid] = 0;
  }
  __syncthreads();

#define STEPD(HB_, BASE_, W_, J_) { uint4 hv = HB_[(BASE_) + (J_)];  \
    a0 = fdot2(BC(hv.x), BC(W_.x), a0);                              \
    a1 = fdot2(BC(hv.y), BC(W_.y), a1);                              \
    a2 = fdot2(BC(hv.z), BC(W_.z), a2);                              \
    a3 = fdot2(BC(hv.w), BC(W_.w), a3); }

  // One full R7 step for batch B_ using state slot P_.
#define BSTEP(P_, B_, CST_, XV_) {                                            \
    const uint4* hb4 = (const uint4*)hbufh[P_];                               \
    float a0 = 0.f, a1 = 0.f, a2 = 0.f, a3 = 0.f;                             \
    /* A-dot: feed-forward half, fills the other batch's latency shadow */    \
    STEPD(hb4, abase, w00, 0)  STEPD(hb4, abase, w01, 1)                      \
    STEPD(hb4, abase, w02, 2)  STEPD(hb4, abase, w03, 3)                      \
    STEPD(hb4, abase, w04, 4)  STEPD(hb4, abase, w05, 5)                      \
    STEPD(hb4, abase, w06, 6)  STEPD(hb4, abase, w07, 7)                      \
    STEPD(hb4, abase, w08, 8)  STEPD(hb4, abase, w09, 9)                      \
    STEPD(hb4, abase, w10, 10) STEPD(hb4, abase, w11, 11)                     \
    STEPD(hb4, abase, w12, 12) STEPD(hb4, abase, w13, 13)                     \
    STEPD(hb4, abase, w14, 14) STEPD(hb4, abase, w15, 15)                     \
    /* B-stage: poll remote h(t-1); own slice self-staged at last elem */     \
    if (t > 0 && tid >= 256) {                                                \
      const int col = tid - 256;                                              \
      if ((col >> 6) != s) {                                                  \
        const unsigned tg = (unsigned)(t - 1);                                \
        const unsigned* pw = L                                                \
          ? H2R + ((size_t)((t - 1) & 3) * 32 + (B_)) * 256 + col             \
          : H1T + ((size_t)(t - 1) * 32 + (B_)) * 256 + col;                  \
        hbufh[P_][tid] = (unsigned short)poll_tag(pw, tg);                    \
      }                                                                       \
    }                                                                         \
    __syncthreads();                                                          \
    /* B-dot: recurrent half (the only dot on this batch's chain) */          \
    STEPD(hb4, bbase, w16, 0)  STEPD(hb4, bbase, w17, 1)                      \
    STEPD(hb4, bbase, w18, 2)  STEPD(hb4, bbase, w19, 3)                      \
    STEPD(hb4, bbase, w20, 4)  STEPD(hb4, bbase, w21, 5)                      \
    STEPD(hb4, bbase, w22, 6)  STEPD(hb4, bbase, w23, 7)                      \
    STEPD(hb4, bbase, w24, 8)  STEPD(hb4, bbase, w25, 9)                      \
    STEPD(hb4, bbase, w26, 10) STEPD(hb4, bbase, w27, 11)                     \
    STEPD(hb4, bbase, w28, 12) STEPD(hb4, bbase, w29, 13)                     \
    STEPD(hb4, bbase, w30, 14) STEPD(hb4, bbase, w31, 15)                     \
    part[P_][kq][c] = (a0 + a1) + (a2 + a3);                                  \
    /* A-stage(t+1) under the elementwise shadow */                           \
    if (t < 2047 && tid < 256) {                                              \
      if (!L) {                                                               \
        hbufh[P_][tid] = f16b(XV_);                                           \
        if (t + 2 < 2048) {                                                   \
          size_t xi = ((size_t)(B_) * 2048 + (t + 2)) * 256 + tid;            \
          XV_ = ldw(x, xi, fp32);                                             \
        }                                                                     \
      } else {                                                                \
        const unsigned* pw = H1T + ((size_t)(t + 1) * 32 + (B_)) * 256 + tid; \
        hbufh[P_][tid] = (unsigned short)poll_tag(pw, (unsigned)(t + 1));     \
      }                                                                       \
    }                                                                         \
    __syncthreads();                                                          \
    /* elementwise + publish (wave 0); gate order (i, j, f, o) */             \
    if (tid < 64) {                                                           \
      int j = tid;                                                            \
      float gi = part[P_][0][j]       + part[P_][1][j]       + bg[j];         \
      float gj = part[P_][0][64 + j]  + part[P_][1][64 + j]  + bg[64 + j];    \
      float gf = part[P_][0][128 + j] + part[P_][1][128 + j] + bg[128 + j];   \
      float go = part[P_][0][192 + j] + part[P_][1][192 + j] + bg[192 + j];   \
      float cn = (CST_) * sigm(gf + 1.f) + sigm(gi) * tanh_(gj);              \
      CST_ = cn;                                                              \
      float h = tanh_(cn) * sigm(go);                                         \
      unsigned short hb = f16b(h);                                            \
      unsigned val = ((unsigned)t << 16) | (unsigned)hb;                      \
      hbufh[P_][256 + (s << 6) + j] = hb;                                     \
      if (!L) {                                                               \
        __hip_atomic_store(H1T + ((size_t)t * 32 + (B_)) * 256 + s * 64 + j,  \
                           val, __ATOMIC_RELAXED, __HIP_MEMORY_SCOPE_AGENT);  \
      } else {                                                                \
        __hip_atomic_store(                                                   \
            H2R + ((size_t)(t & 3) * 32 + (B_)) * 256 + s * 64 + j,           \
            val, __ATOMIC_RELAXED, __HIP_MEMORY_SCOPE_AGENT);                 \
        size_t oi = ((size_t)(B_) * 2048 + t) * 256 + s * 64 + j;             \
        if (fp32) ((float*)dout)[oi] = h;                                     \
        else      ((unsigned short*)dout)[oi] = f2bf(h);                      \
      }                                                                       \
    }                                                                         \
    /* no trailing barrier: same safety argument as R7 — part/hbuf rewrites   \
       are fenced by this batch's next-iteration barriers. */                 \
  }

  for (int t = 0; t < 2048; ++t) {
    BSTEP(0, b1, cst1, xv1)
    BSTEP(1, b2, cst2, xv2)
  }
#undef BSTEP
#undef STEPD
}

// ----------------------------------------------------------------------------
extern "C" void kernel_launch(void* const* d_in, const int* in_sizes, int n_in,
                              void* d_out, int out_size, void* d_ws, size_t ws_size,
                              hipStream_t stream) {
  const void* x  = d_in[0];   // [32][2048][256]
  const void* W0 = d_in[1];   // [512][1024]
  const void* b0 = d_in[2];   // [1024]
  const void* W1 = d_in[3];   // [512][1024]
  const void* b1 = d_in[4];   // [1024]

  char* p = (char*)d_ws;                                   // ~69.3 MB total
  unsigned* Wrec = (unsigned*)p; p += (size_t)524288 * 4;  // 2 MB packed f16x2
  unsigned* H1T  = (unsigned*)p; p += (size_t)2048 * 32 * 256 * 4;  // 67.1 MB
  unsigned* H2R  = (unsigned*)p; p += (size_t)4 * 32 * 256 * 4;     // 128 KB
  float* bias0   = (float*)p;    p += 4096;
  float* bias1   = (float*)p;    p += 4096;
  int* dflag     = (int*)p;      p += 256;

  detect<<<1, 256, 0, stream>>>((const unsigned short*)x, dflag);
  prep<<<dim3(2048, 2), 256, 0, stream>>>(W0, W1, b0, b1, dflag,
                                          Wrec, bias0, bias1);
  recur<<<128, 512, 0, stream>>>(x, Wrec, bias0, bias1,
                                 H1T, H2R, d_out, dflag);
}

// Round 7
// 3159.092 us; speedup vs baseline: 1.5985x; 1.5985x over previous
//
#include <hip/hip_runtime.h>
#include <hip/hip_bf16.h>
#include <hip/hip_fp16.h>

// ============================================================================
// 2-layer LSTM (TF BasicLSTMCell, forget_bias=1), B=32, T=2048, D=H=256.
// R12: R7 structure (best: 3176us) + ONE change: publish via agent-scope
//   atomicExch instead of atomic store.
//   Mechanism: a relaxed agent STORE lands dirty in the producer's XCD L2;
//   the consumer's agent load goes to the MALL, which must snoop the
//   producer's L2 and pull the writeback -> Lambda ~= RT_probe + RT_snoop.
//   An agent-scope RMW (atomicExch) EXECUTES AT the coherence point: the
//   value is at the MALL immediately, consumer probes hit directly, snoop
//   hop gone. Producer doesn't wait (result unused -> no vmcnt stall);
//   traffic = 64 words/WG/step (unlike R10, whose CONSUMER-side CAS polls
//   dirtied lines every round -> 1.8GB writebacks).
//   Post-mortems driving this: R6 (reg pinning null), R7 (on-chain dot
//   halved: null -> latency-bound), R8/R9 (asm sc0 poll: container death),
//   R10 (CAS poll: +28%), R11 (batch interleave: chains coupled by shared
//   barriers, +59% — and structurally could never beat the per-batch chain).
//   Unchanged from R7: 256 WGs = 2L x 4slice x 32batch, 512 thr; A/B split
//   dot (A off-chain); x(t+1) prefetch; 4-outstanding agent-scope poll;
//   tagged words (t<<16|f16, poison-safe); wave0 own-slice LDS self-stage;
//   H1 write-once trace; H2 depth-4 ring; prep/Wrec layout; detect.
// ============================================================================

typedef _Float16 half_t;
typedef __attribute__((ext_vector_type(2))) _Float16 h2v;

static __device__ __forceinline__ float bf2f(unsigned short u) {
  union { unsigned u; float f; } v; v.u = ((unsigned)u) << 16; return v.f;
}
static __device__ __forceinline__ unsigned short f2bf(float f) {
  union { float f; unsigned u; } v; v.f = f;
  unsigned r = v.u + 0x7fffu + ((v.u >> 16) & 1u);
  return (unsigned short)(r >> 16);
}
static __device__ __forceinline__ float ldw(const void* p, long i, int fp32) {
  return fp32 ? ((const float*)p)[i] : bf2f(((const unsigned short*)p)[i]);
}
static __device__ __forceinline__ unsigned short f16b(float f) {
  return __builtin_bit_cast(unsigned short, (half_t)f);
}
static __device__ __forceinline__ h2v BC(unsigned u) {
  return __builtin_bit_cast(h2v, u);
}
static __device__ __forceinline__ float rcpf(float x) { return __builtin_amdgcn_rcpf(x); }
static __device__ __forceinline__ float sigm(float x) { return rcpf(1.f + __expf(-x)); }
static __device__ __forceinline__ float tanh_(float x) {
  float e = __expf(-2.f * fabsf(x));
  float t = (1.f - e) * rcpf(1.f + e);
  return copysignf(t, x);
}
static __device__ __forceinline__ float fdot2(h2v a, h2v b, float c) {
#if __has_builtin(__builtin_amdgcn_fdot2)
  return __builtin_amdgcn_fdot2(a, b, c, false);
#else
  return c + (float)a.x * (float)b.x + (float)a.y * (float)b.y;
#endif
}
static __device__ __forceinline__ unsigned ald(const unsigned* p) {
  return __hip_atomic_load(p, __ATOMIC_RELAXED, __HIP_MEMORY_SCOPE_AGENT);
}
// 4-deep pipelined tag poll: 4 outstanding loads per round, staggered checks.
static __device__ __forceinline__ unsigned poll_tag(const unsigned* p, unsigned tg) {
  unsigned v = ald(p);
  while ((v >> 16) != tg) {
    unsigned a = ald(p);
    unsigned b = ald(p);
    unsigned c = ald(p);
    unsigned d = ald(p);
    if ((a >> 16) == tg) { v = a; break; }
    if ((b >> 16) == tg) { v = b; break; }
    if ((c >> 16) == tg) { v = c; break; }
    v = d;
  }
  return v;
}
// Publish at the coherence point: agent-scope RMW (value lands at MALL at
// execute time; no dirty-L2 snoop on the consumer's probe path).
static __device__ __forceinline__ void publish(unsigned* p, unsigned val) {
  (void)__hip_atomic_exchange(p, val, __ATOMIC_RELAXED,
                              __HIP_MEMORY_SCOPE_AGENT);
}

// ---------------------------------------------------------------- detect ----
__global__ __launch_bounds__(256) void detect(const unsigned short* __restrict__ x,
                                              int* __restrict__ flag) {
  __shared__ int cnt;
  if (threadIdx.x == 0) cnt = 0;
  __syncthreads();
  int c = 0;
#pragma unroll
  for (int i = 0; i < 8; ++i) {
    unsigned short u = x[threadIdx.x * 8 + i];
    c += (((u >> 7) & 0xFF) >= 192) ? 1 : 0;
  }
  atomicAdd(&cnt, c);
  __syncthreads();
  if (threadIdx.x == 0) *flag = (cnt > 16) ? 1 : 0;
}

// ------------------------------------------------------------------ prep ----
// task0 (y=0): Wrec packed u32 words. u = (sL*512 + tid)*128 + i, sL=L*4+s.
//   kq=tid>>8, c=tid&255, col=(c>>6)*256 + s*64 + (c&63).
//   word i -> part p=i>>6 (0=feed-forward rows 0..255, 1=recurrent rows
//   256..511), ii=i&63, rows p*256 + kq*128 + 2*ii, +1. word = lo | hi<<16.
// task1 (y=1): biases -> fp32.
// ----------------------------------------------------------------------------
__global__ __launch_bounds__(256) void prep(
    const void* __restrict__ W0, const void* __restrict__ W1,
    const void* __restrict__ b0, const void* __restrict__ b1,
    const int* __restrict__ dtf,
    unsigned* __restrict__ Wrec, float* __restrict__ bias0,
    float* __restrict__ bias1)
{
  const int fp32 = *dtf;
  int id = blockIdx.x * 256 + threadIdx.x;
  if (blockIdx.y == 0) {
    int i  = id & 127;
    int tid = (id >> 7) & 511;
    int sL = id >> 16;                 // 0..7 = L*4+s
    int L = sL >> 2, s = sL & 3;
    int kq = tid >> 8, c = tid & 255;
    int col = ((c >> 6) << 8) + s * 64 + (c & 63);
    int p  = i >> 6, ii = i & 63;
    long r0 = (long)(p * 256 + kq * 128 + 2 * ii) * 1024 + col;
    const void* W = L ? W1 : W0;
    unsigned lo = f16b(ldw(W, r0, fp32));
    unsigned hi = f16b(ldw(W, r0 + 1024, fp32));
    Wrec[id] = lo | (hi << 16);
  } else {
    if (id < 1024)       bias0[id] = ldw(b0, id, fp32);
    else if (id < 2048)  bias1[id - 1024] = ldw(b1, id - 1024, fp32);
  }
}

// ----------------------------------------------------------------- recur ----
__global__ __launch_bounds__(512) void recur(
    const void* __restrict__ x, const unsigned* __restrict__ Wrec,
    const float* __restrict__ bias0, const float* __restrict__ bias1,
    unsigned* H1T, unsigned* H2R,
    void* __restrict__ dout, const int* __restrict__ dtf)
{
  const int fp32 = *dtf;
  const int bi = blockIdx.x;
  const int L = bi >> 7, sL = bi >> 5, s = sL & 3, b = bi & 31;
  const int tid = threadIdx.x;
  const int kq = tid >> 8, c = tid & 255;
  const int abase = kq << 4;        // A-dot hbufu4 base (rows 0..255)
  const int bbase = 32 + (kq << 4); // B-dot hbufu4 base (rows 256..511)

  __shared__ __align__(16) unsigned short hbufh[512];
  __shared__ float part[2][256];
  __shared__ float bg[256];

  // ---- weights: w00-w15 feed-forward rows, w16-w31 recurrent rows ----
  const uint4* wp4 = (const uint4*)Wrec + ((size_t)sL * 512 + tid) * 32;
  uint4 w00 = wp4[0],  w01 = wp4[1],  w02 = wp4[2],  w03 = wp4[3];
  uint4 w04 = wp4[4],  w05 = wp4[5],  w06 = wp4[6],  w07 = wp4[7];
  uint4 w08 = wp4[8],  w09 = wp4[9],  w10 = wp4[10], w11 = wp4[11];
  uint4 w12 = wp4[12], w13 = wp4[13], w14 = wp4[14], w15 = wp4[15];
  uint4 w16 = wp4[16], w17 = wp4[17], w18 = wp4[18], w19 = wp4[19];
  uint4 w20 = wp4[20], w21 = wp4[21], w22 = wp4[22], w23 = wp4[23];
  uint4 w24 = wp4[24], w25 = wp4[25], w26 = wp4[26], w27 = wp4[27];
  uint4 w28 = wp4[28], w29 = wp4[29], w30 = wp4[30], w31 = wp4[31];

  if (tid < 256) {
    int scol = ((c >> 6) << 8) + s * 64 + (c & 63);
    bg[c] = (L ? bias1 : bias0)[scol];
  }

  const uint4* hbufu4 = (const uint4*)hbufh;
  float cst = 0.f;

  // ---- prologue: stage A(0), zero B (h(-1)=0), prefetch x(1) ----
  float xv = 0.f;
  if (tid < 256) {
    if (!L) {
      size_t xi = (size_t)b * 2048 * 256 + tid;
      hbufh[tid] = f16b(fp32 ? ((const float*)x)[xi]
                             : bf2f(((const unsigned short*)x)[xi]));
      size_t xj = xi + 256;  // x(1)
      xv = fp32 ? ((const float*)x)[xj] : bf2f(((const unsigned short*)x)[xj]);
    } else {
      unsigned v = poll_tag(H1T + (size_t)b * 256 + tid, 0u);
      hbufh[tid] = (unsigned short)v;
    }
  } else {
    hbufh[tid] = 0;
  }
  __syncthreads();

  for (int t = 0; t < 2048; ++t) {
    // ---- A-dot: feed-forward half, off the latency chain ----
    float a0 = 0.f, a1 = 0.f, a2 = 0.f, a3 = 0.f;
#define STEPD(BASE_, W_, J_) { uint4 hv = hbufu4[BASE_ + J_];  \
    a0 = fdot2(BC(hv.x), BC(W_.x), a0);                        \
    a1 = fdot2(BC(hv.y), BC(W_.y), a1);                        \
    a2 = fdot2(BC(hv.z), BC(W_.z), a2);                        \
    a3 = fdot2(BC(hv.w), BC(W_.w), a3); }
    STEPD(abase, w00, 0)  STEPD(abase, w01, 1)  STEPD(abase, w02, 2)  STEPD(abase, w03, 3)
    STEPD(abase, w04, 4)  STEPD(abase, w05, 5)  STEPD(abase, w06, 6)  STEPD(abase, w07, 7)
    STEPD(abase, w08, 8)  STEPD(abase, w09, 9)  STEPD(abase, w10, 10) STEPD(abase, w11, 11)
    STEPD(abase, w12, 12) STEPD(abase, w13, 13) STEPD(abase, w14, 14) STEPD(abase, w15, 15)

    // ---- poll remote h(t-1) slices, stage to B region (own slice was
    //      LDS-staged by wave0 at elem time last iteration) ----
    if (t > 0 && tid >= 256) {
      const int col = tid - 256;
      if ((col >> 6) != s) {
        const unsigned tg = (unsigned)(t - 1);
        const unsigned* pw = L
          ? H2R + ((size_t)((t - 1) & 3) * 32 + b) * 256 + col
          : H1T + ((size_t)(t - 1) * 32 + b) * 256 + col;
        hbufh[tid] = (unsigned short)poll_tag(pw, tg);
      }
    }
    __syncthreads();  // bar2: B staged; A region now safe to rewrite

    // ---- B-dot: recurrent half (the only dot on the serial chain) ----
    STEPD(bbase, w16, 0)  STEPD(bbase, w17, 1)  STEPD(bbase, w18, 2)  STEPD(bbase, w19, 3)
    STEPD(bbase, w20, 4)  STEPD(bbase, w21, 5)  STEPD(bbase, w22, 6)  STEPD(bbase, w23, 7)
    STEPD(bbase, w24, 8)  STEPD(bbase, w25, 9)  STEPD(bbase, w26, 10) STEPD(bbase, w27, 11)
    STEPD(bbase, w28, 12) STEPD(bbase, w29, 13) STEPD(bbase, w30, 14) STEPD(bbase, w31, 15)
#undef STEPD
    part[kq][c] = (a0 + a1) + (a2 + a3);

    // ---- stage A(t+1) under the elementwise shadow ----
    if (t < 2047 && tid < 256) {
      if (!L) {
        hbufh[tid] = f16b(xv);
        if (t + 2 < 2048) {
          size_t xi = ((size_t)b * 2048 + (t + 2)) * 256 + tid;
          xv = fp32 ? ((const float*)x)[xi]
                    : bf2f(((const unsigned short*)x)[xi]);
        }
      } else {
        unsigned v = poll_tag(H1T + ((size_t)(t + 1) * 32 + b) * 256 + tid,
                              (unsigned)(t + 1));
        hbufh[tid] = (unsigned short)v;
      }
    }
    __syncthreads();  // bar3: part + A(t+1) staged

    // ---- elementwise + publish (wave 0); gate order (i, j, f, o) ----
    if (tid < 64) {
      int j = tid;
      float gi = part[0][j]       + part[1][j]       + bg[j];
      float gj = part[0][64 + j]  + part[1][64 + j]  + bg[64 + j];
      float gf = part[0][128 + j] + part[1][128 + j] + bg[128 + j];
      float go = part[0][192 + j] + part[1][192 + j] + bg[192 + j];
      float cn = cst * sigm(gf + 1.f) + sigm(gi) * tanh_(gj);
      cst = cn;
      float h = tanh_(cn) * sigm(go);
      unsigned short hb = f16b(h);
      unsigned val = ((unsigned)t << 16) | (unsigned)hb;
      // own-slice columns straight into next step's LDS B region
      hbufh[256 + (s << 6) + j] = hb;
      if (!L) {
        publish(H1T + ((size_t)t * 32 + b) * 256 + s * 64 + j, val);
      } else {
        publish(H2R + ((size_t)(t & 3) * 32 + b) * 256 + s * 64 + j, val);
        size_t oi = ((size_t)b * 2048 + t) * 256 + s * 64 + j;
        if (fp32) ((float*)dout)[oi] = h;
        else      ((unsigned short*)dout)[oi] = f2bf(h);
      }
    }
    // no trailing barrier: next iter's A-dot reads A region (staged before
    // bar3); B staging (next iter) is after this thread's bar3; part rewrite
    // (next iter) is after bar2(t+1), which wave0 reaches only after its
    // elementwise reads complete.
  }
}

// ----------------------------------------------------------------------------
extern "C" void kernel_launch(void* const* d_in, const int* in_sizes, int n_in,
                              void* d_out, int out_size, void* d_ws, size_t ws_size,
                              hipStream_t stream) {
  const void* x  = d_in[0];   // [32][2048][256]
  const void* W0 = d_in[1];   // [512][1024]
  const void* b0 = d_in[2];   // [1024]
  const void* W1 = d_in[3];   // [512][1024]
  const void* b1 = d_in[4];   // [1024]

  char* p = (char*)d_ws;                                   // ~69.3 MB total
  unsigned* Wrec = (unsigned*)p; p += (size_t)524288 * 4;  // 2 MB packed f16x2
  unsigned* H1T  = (unsigned*)p; p += (size_t)2048 * 32 * 256 * 4;  // 67.1 MB
  unsigned* H2R  = (unsigned*)p; p += (size_t)4 * 32 * 256 * 4;     // 128 KB
  float* bias0   = (float*)p;    p += 4096;
  float* bias1   = (float*)p;    p += 4096;
  int* dflag     = (int*)p;      p += 256;

  detect<<<1, 256, 0, stream>>>((const unsigned short*)x, dflag);
  prep<<<dim3(2048, 2), 256, 0, stream>>>(W0, W1, b0, b1, dflag,
                                          Wrec, bias0, bias1);
  recur<<<256, 512, 0, stream>>>(x, Wrec, bias0, bias1,
                                 H1T, H2R, d_out, dflag);
}